// Round 3
// baseline (234.082 us; speedup 1.0000x reference)
//
#include <hip/hip_runtime.h>
#include <hip/hip_bf16.h>

// Problem constants (match reference)
#define B_  16
#define NX_ 1024
#define NY_ 4096
#define C_  256
#define CS_ 128
#define H_  256
#define M_  (B_ * NY_)     // 65536 rows through the MLP
#define K1_ (C_ + CS_)     // 384
#define K2_ (H_)           // 256

using short8  = __attribute__((ext_vector_type(8))) short;
using floatx4 = __attribute__((ext_vector_type(4))) float;

__device__ __forceinline__ unsigned short f2bf(float f) {
    unsigned int u = __float_as_uint(f);
    unsigned int r = (u + 0x7fffu + ((u >> 16) & 1u)) >> 16;
    return (unsigned short)r;
}

// ---------------------------------------------------------------------------
// Kernel 1: KNN(k=3) + inverse-distance interpolation + concat with x_skip.
// One wave per fine point; 4 waves (256 threads) per block; coarse positions
// staged in LDS. Distance formula replicates the reference's Gram trick
// ((|y|^2 + |x|^2) - 2*dot) with _rn ops to prevent FMA contraction, and
// ties break by lower index (like lax.top_k).
// Output: h0 [M_][384] bf16, cols 0..255 = interp, 256..383 = x_skip.
// ---------------------------------------------------------------------------
__global__ __launch_bounds__(256) void knn_interp_kernel(
    const float* __restrict__ x, const float* __restrict__ pos,
    const float* __restrict__ x_skip, const float* __restrict__ pos_skip,
    unsigned short* __restrict__ h0)
{
    __shared__ float spx[NX_], spy[NX_], spz[NX_], spn[NX_];   // 16 KiB
    const int tid  = threadIdx.x;
    const int wave = tid >> 6;
    const int lane = tid & 63;
    const int b    = blockIdx.x >> 10;        // 1024 blocks per batch

    for (int j = tid; j < NX_; j += 256) {
        const float* pp = pos + (size_t)(b * NX_ + j) * 3;
        float px = pp[0], py = pp[1], pz = pp[2];
        spx[j] = px; spy[j] = py; spz[j] = pz;
        spn[j] = __fadd_rn(__fadd_rn(__fmul_rn(px, px), __fmul_rn(py, py)),
                           __fmul_rn(pz, pz));
    }
    __syncthreads();

    const int y = blockIdx.x * 4 + wave;      // fine point index
    const float* q = pos_skip + (size_t)y * 3;
    const float qx = q[0], qy = q[1], qz = q[2];
    const float qn = __fadd_rn(__fadd_rn(__fmul_rn(qx, qx), __fmul_rn(qy, qy)),
                               __fmul_rn(qz, qz));

    // per-lane top-3 (sorted ascending, lex tie-break by index implicit since
    // j increases and we use strict <)
    float bd0 = 3.4e38f, bd1 = 3.4e38f, bd2 = 3.4e38f;
    int   bi0 = 0x7fffffff, bi1 = 0x7fffffff, bi2 = 0x7fffffff;
    #pragma unroll
    for (int t = 0; t < NX_ / 64; ++t) {
        const int j = lane + t * 64;
        float dot = __fadd_rn(__fadd_rn(__fmul_rn(qx, spx[j]),
                                        __fmul_rn(qy, spy[j])),
                              __fmul_rn(qz, spz[j]));
        float d2 = __fsub_rn(__fadd_rn(qn, spn[j]), __fmul_rn(2.0f, dot));
        if (d2 < bd2) {
            if (d2 < bd1) {
                bd2 = bd1; bi2 = bi1;
                if (d2 < bd0) { bd1 = bd0; bi1 = bi0; bd0 = d2; bi0 = j; }
                else          { bd1 = d2;  bi1 = j; }
            } else { bd2 = d2; bi2 = j; }
        }
    }

    // 3 rounds of wave-wide lexicographic argmin with pop
    float nd0, nd1, nd2; int ni0, ni1, ni2;
    #pragma unroll
    for (int kk = 0; kk < 3; ++kk) {
        float cd = bd0; int ci = bi0;
        #pragma unroll
        for (int m = 1; m < 64; m <<= 1) {
            float od = __shfl_xor(cd, m);
            int   oi = __shfl_xor(ci, m);
            if (od < cd || (od == cd && oi < ci)) { cd = od; ci = oi; }
        }
        if (kk == 0) { nd0 = cd; ni0 = ci; }
        else if (kk == 1) { nd1 = cd; ni1 = ci; }
        else { nd2 = cd; ni2 = ci; }
        if (bi0 == ci) {   // pop from the owning lane
            bd0 = bd1; bi0 = bi1;
            bd1 = bd2; bi1 = bi2;
            bd2 = 3.4e38f; bi2 = 0x7fffffff;
        }
    }

    const float w0 = 1.0f / (sqrtf(fmaxf(nd0, 0.0f)) + 1e-8f);
    const float w1 = 1.0f / (sqrtf(fmaxf(nd1, 0.0f)) + 1e-8f);
    const float w2 = 1.0f / (sqrtf(fmaxf(nd2, 0.0f)) + 1e-8f);
    const float inv_den = 1.0f / (w0 + w1 + w2 + 1e-8f);

    // gather features: lane handles channels [lane*4, lane*4+4)
    const float* fb = x + (size_t)b * NX_ * C_;
    const float4 f0 = *(const float4*)(fb + (size_t)ni0 * C_ + lane * 4);
    const float4 f1 = *(const float4*)(fb + (size_t)ni1 * C_ + lane * 4);
    const float4 f2 = *(const float4*)(fb + (size_t)ni2 * C_ + lane * 4);

    ushort4 o;
    o.x = f2bf((w0 * f0.x + w1 * f1.x + w2 * f2.x) * inv_den);
    o.y = f2bf((w0 * f0.y + w1 * f1.y + w2 * f2.y) * inv_den);
    o.z = f2bf((w0 * f0.z + w1 * f1.z + w2 * f2.z) * inv_den);
    o.w = f2bf((w0 * f0.w + w1 * f1.w + w2 * f2.w) * inv_den);
    *(ushort4*)(h0 + (size_t)y * K1_ + lane * 4) = o;

    // skip features: lane handles channels [lane*2, lane*2+2)
    const float2 s2 = *(const float2*)(x_skip + (size_t)y * CS_ + lane * 2);
    ushort2 os;
    os.x = f2bf(s2.x);
    os.y = f2bf(s2.y);
    *(ushort2*)(h0 + (size_t)y * K1_ + C_ + lane * 2) = os;
}

// ---------------------------------------------------------------------------
// Kernel 2: cast + transpose weights to bf16 [N][K] so MFMA B-fragments read
// K-contiguous 16B from LDS.
// ---------------------------------------------------------------------------
__global__ __launch_bounds__(256) void prep_w(
    const float* __restrict__ W1, const float* __restrict__ W2,
    unsigned short* __restrict__ W1t, unsigned short* __restrict__ W2t)
{
    int id = blockIdx.x * 256 + threadIdx.x;
    if (id < K1_ * H_) {      // 98304: W1t[n][k] = W1[k][n]
        int n = id / K1_, k = id - n * K1_;
        W1t[id] = f2bf(W1[(size_t)k * H_ + n]);
    }
    if (id < K2_ * H_) {      // 65536: W2t[n][k] = W2[k][n]
        int n = id >> 8, k = id & 255;
        W2t[id] = f2bf(W2[(size_t)k * H_ + n]);
    }
}

// ---------------------------------------------------------------------------
// Kernels 3/4: bf16 MFMA GEMM  out[M][256] = relu(A[M][K] * Bt[256][K]^T + b)
// Block: 256 threads = 4 waves, tile 64(M) x 64(N), BK=32.
// Wave w -> (wr=w>>1, wc=w&1) owns a 32x32 quadrant = 2x2 16x16 fragments.
// mfma_f32_16x16x32_bf16: A lane = A[lane&15][(lane>>4)*8 + i],
//                         B lane = B[(lane>>4)*8 + i][lane&15],
//                         D lane reg r = D[(lane>>4)*4 + r][lane&15]  (m89).
// ---------------------------------------------------------------------------
template<int K, int OUT_BF16>
__global__ __launch_bounds__(256) void gemm_bias_relu(
    const unsigned short* __restrict__ A,   // [M][K] bf16
    const unsigned short* __restrict__ Bt,  // [256][K] bf16
    const float* __restrict__ bias,         // [256]
    void* __restrict__ outp)                // [M][256] bf16 or f32
{
    constexpr int LDSK = 48;                // padded K-stride (96 B, 16B mult.)
    __shared__ unsigned short As[64 * LDSK];
    __shared__ unsigned short Bs[64 * LDSK];

    const int tid  = threadIdx.x;
    const int lane = tid & 63;
    const int wave = tid >> 6;
    const int wr = wave >> 1, wc = wave & 1;
    const int m0 = blockIdx.x * 64;
    const int n0 = blockIdx.y * 64;

    const int lrow = tid >> 2;              // 0..63
    const int lcol = (tid & 3) * 8;         // 0,8,16,24
    const unsigned short* Ag = A  + (size_t)(m0 + lrow) * K + lcol;
    const unsigned short* Bg = Bt + (size_t)(n0 + lrow) * K + lcol;
    unsigned short* AsW = As + lrow * LDSK + lcol;
    unsigned short* BsW = Bs + lrow * LDSK + lcol;

    const int r16 = lane & 15, qk = lane >> 4;
    const unsigned short* AsR = As + (wr * 32 + r16) * LDSK + qk * 8;
    const unsigned short* BsR = Bs + (wc * 32 + r16) * LDSK + qk * 8;

    floatx4 acc[2][2] = {};

    for (int kt = 0; kt < K; kt += 32) {
        const uint4 av = *(const uint4*)(Ag + kt);
        const uint4 bv = *(const uint4*)(Bg + kt);
        __syncthreads();
        *(uint4*)AsW = av;
        *(uint4*)BsW = bv;
        __syncthreads();
        short8 a0 = *(const short8*)(AsR);
        short8 a1 = *(const short8*)(AsR + 16 * LDSK);
        short8 b0 = *(const short8*)(BsR);
        short8 b1 = *(const short8*)(BsR + 16 * LDSK);
        acc[0][0] = __builtin_amdgcn_mfma_f32_16x16x32_bf16(a0, b0, acc[0][0], 0, 0, 0);
        acc[0][1] = __builtin_amdgcn_mfma_f32_16x16x32_bf16(a0, b1, acc[0][1], 0, 0, 0);
        acc[1][0] = __builtin_amdgcn_mfma_f32_16x16x32_bf16(a1, b0, acc[1][0], 0, 0, 0);
        acc[1][1] = __builtin_amdgcn_mfma_f32_16x16x32_bf16(a1, b1, acc[1][1], 0, 0, 0);
    }

    #pragma unroll
    for (int m = 0; m < 2; ++m) {
        #pragma unroll
        for (int n = 0; n < 2; ++n) {
            const int gc = n0 + wc * 32 + n * 16 + r16;
            const float bv = bias[gc];
            #pragma unroll
            for (int r = 0; r < 4; ++r) {
                const int gr = m0 + wr * 32 + m * 16 + qk * 4 + r;
                float v = acc[m][n][r] + bv;
                v = fmaxf(v, 0.0f);
                if (OUT_BF16)
                    ((unsigned short*)outp)[(size_t)gr * H_ + gc] = f2bf(v);
                else
                    ((float*)outp)[(size_t)gr * H_ + gc] = v;
            }
        }
    }
}

// ---------------------------------------------------------------------------
extern "C" void kernel_launch(void* const* d_in, const int* in_sizes, int n_in,
                              void* d_out, int out_size, void* d_ws, size_t ws_size,
                              hipStream_t stream)
{
    const float* x        = (const float*)d_in[0];
    const float* pos      = (const float*)d_in[1];
    const float* x_skip   = (const float*)d_in[3];
    const float* pos_skip = (const float*)d_in[4];
    const float* W1       = (const float*)d_in[6];
    const float* b1       = (const float*)d_in[7];
    const float* W2       = (const float*)d_in[8];
    const float* b2       = (const float*)d_in[9];

    char* ws = (char*)d_ws;
    unsigned short* h0  = (unsigned short*)(ws);                         // 65536*384*2 = 48 MiB
    unsigned short* h1  = (unsigned short*)(ws + 50331648);              // 65536*256*2 = 32 MiB
    unsigned short* W1t = (unsigned short*)(ws + 50331648 + 33554432);   // 192 KiB
    unsigned short* W2t = (unsigned short*)(ws + 83886080 + 196608);     // 128 KiB

    hipLaunchKernelGGL(knn_interp_kernel, dim3(M_ / 4), dim3(256), 0, stream,
                       x, pos, x_skip, pos_skip, h0);
    hipLaunchKernelGGL(prep_w, dim3((K1_ * H_ + 255) / 256), dim3(256), 0, stream,
                       W1, W2, W1t, W2t);
    hipLaunchKernelGGL((gemm_bias_relu<K1_, 1>), dim3(M_ / 64, H_ / 64), dim3(256),
                       0, stream, h0, W1t, b1, h1);
    hipLaunchKernelGGL((gemm_bias_relu<K2_, 0>), dim3(M_ / 64, H_ / 64), dim3(256),
                       0, stream, h1, W2t, b2, (float*)d_out);
}

// Round 4
// 230.194 us; speedup vs baseline: 1.0169x; 1.0169x over previous
//
#include <hip/hip_runtime.h>
#include <hip/hip_bf16.h>

// Problem constants (match reference)
#define B_  16
#define NX_ 1024
#define NY_ 4096
#define C_  256
#define CS_ 128
#define H_  256
#define M_  (B_ * NY_)     // 65536 rows through the MLP
#define K1_ (C_ + CS_)     // 384
#define K2_ (H_)           // 256

using short8  = __attribute__((ext_vector_type(8))) short;
using floatx4 = __attribute__((ext_vector_type(4))) float;

__device__ __forceinline__ unsigned short f2bf(float f) {
    unsigned int u = __float_as_uint(f);
    unsigned int r = (u + 0x7fffu + ((u >> 16) & 1u)) >> 16;
    return (unsigned short)r;
}

// global -> LDS async 16B copy (dest must be linear: wave base + lane*16)
typedef const __attribute__((address_space(1))) void gas_t;
typedef __attribute__((address_space(3))) void las_t;
__device__ __forceinline__ void gload_lds16(const void* g, void* l) {
    __builtin_amdgcn_global_load_lds((gas_t*)g, (las_t*)l, 16, 0, 0);
}

// ---------------------------------------------------------------------------
// Kernel 1: KNN select. One THREAD per fine point (no wave argmin), coarse
// positions packed float4 in LDS (broadcast reads). 512 threads / block =
// 256 points, each point scanned by 2 threads (half each), merged in LDS.
// Distance formula replicates reference Gram trick with _rn ops; strict-<
// insertion over ascending j keeps earliest index on ties (lax.top_k).
// Writes idx4[y]=(i0,i1,i2,0), wgt4[y]=(w0,w1,w2,inv_den).
// ---------------------------------------------------------------------------
__global__ __launch_bounds__(512) void knn_select(
    const float* __restrict__ pos, const float* __restrict__ pos_skip,
    int4* __restrict__ idx4, float4* __restrict__ wgt4)
{
    __shared__ float4 sp[NX_];          // 16 KiB (px,py,pz,|p|^2)
    __shared__ float  m_d[3][256];      // half-1 candidates
    __shared__ int    m_i[3][256];

    const int tid  = threadIdx.x;
    const int p    = tid & 255;          // point slot in block
    const int half = tid >> 8;           // 0 or 1
    const int y    = blockIdx.x * 256 + p;
    const int b    = y >> 12;            // cloud (4096 fine pts per cloud)

    for (int j = tid; j < NX_; j += 512) {
        const float* pp = pos + (size_t)(b * NX_ + j) * 3;
        float px = pp[0], py = pp[1], pz = pp[2];
        float pn = __fadd_rn(__fadd_rn(__fmul_rn(px, px), __fmul_rn(py, py)),
                             __fmul_rn(pz, pz));
        sp[j] = make_float4(px, py, pz, pn);
    }
    __syncthreads();

    const float* q = pos_skip + (size_t)y * 3;
    const float qx = q[0], qy = q[1], qz = q[2];
    const float qn = __fadd_rn(__fadd_rn(__fmul_rn(qx, qx), __fmul_rn(qy, qy)),
                               __fmul_rn(qz, qz));

    float bd0 = 3.4e38f, bd1 = 3.4e38f, bd2 = 3.4e38f;
    int   bi0 = 0x7fffffff, bi1 = 0x7fffffff, bi2 = 0x7fffffff;
    const int j0 = half * 512;
    #pragma unroll 4
    for (int t = 0; t < 512; ++t) {
        const int j = j0 + t;
        const float4 pv = sp[j];
        float dot = __fadd_rn(__fadd_rn(__fmul_rn(qx, pv.x),
                                        __fmul_rn(qy, pv.y)),
                              __fmul_rn(qz, pv.z));
        float d2 = __fsub_rn(__fadd_rn(qn, pv.w), __fmul_rn(2.0f, dot));
        if (d2 < bd2) {
            if (d2 < bd1) {
                bd2 = bd1; bi2 = bi1;
                if (d2 < bd0) { bd1 = bd0; bi1 = bi0; bd0 = d2; bi0 = j; }
                else          { bd1 = d2;  bi1 = j; }
            } else { bd2 = d2; bi2 = j; }
        }
    }

    if (half == 1) {
        m_d[0][p] = bd0; m_d[1][p] = bd1; m_d[2][p] = bd2;
        m_i[0][p] = bi0; m_i[1][p] = bi1; m_i[2][p] = bi2;
    }
    __syncthreads();
    if (half == 0) {
        const float a0 = bd0, a1 = bd1, a2 = bd2;
        const int   ia0 = bi0, ia1 = bi1, ia2 = bi2;
        const float b0 = m_d[0][p], b1 = m_d[1][p], b2 = m_d[2][p];
        const int   ib0 = m_i[0][p], ib1 = m_i[1][p], ib2 = m_i[2][p];
        float d0, d1, d2; int n0, n1, n2;
        if (a0 <= b0) {
            d0 = a0; n0 = ia0;
            if (a1 <= b0) { d1 = a1; n1 = ia1;
                bool c = (a2 <= b0); d2 = c ? a2 : b0; n2 = c ? ia2 : ib0; }
            else          { d1 = b0; n1 = ib0;
                bool c = (a1 <= b1); d2 = c ? a1 : b1; n2 = c ? ia1 : ib1; }
        } else {
            d0 = b0; n0 = ib0;
            if (a0 <= b1) { d1 = a0; n1 = ia0;
                bool c = (a1 <= b1); d2 = c ? a1 : b1; n2 = c ? ia1 : ib1; }
            else          { d1 = b1; n1 = ib1;
                bool c = (a0 <= b2); d2 = c ? a0 : b2; n2 = c ? ia0 : ib2; }
        }
        const float w0 = 1.0f / (sqrtf(fmaxf(d0, 0.0f)) + 1e-8f);
        const float w1 = 1.0f / (sqrtf(fmaxf(d1, 0.0f)) + 1e-8f);
        const float w2 = 1.0f / (sqrtf(fmaxf(d2, 0.0f)) + 1e-8f);
        const float inv_den = 1.0f / (w0 + w1 + w2 + 1e-8f);
        idx4[y] = make_int4(n0, n1, n2, 0);
        wgt4[y] = make_float4(w0, w1, w2, inv_den);
    }
}

// ---------------------------------------------------------------------------
// Kernel 2: gather 3 feature rows per point, blend, concat x_skip -> h0 bf16.
// One wave per point, coalesced float4 gathers (x is L2-resident per cloud).
// ---------------------------------------------------------------------------
__global__ __launch_bounds__(256) void gather_concat(
    const float* __restrict__ x, const float* __restrict__ x_skip,
    const int4* __restrict__ idx4, const float4* __restrict__ wgt4,
    unsigned short* __restrict__ h0)
{
    const int wave = threadIdx.x >> 6, lane = threadIdx.x & 63;
    const int y = blockIdx.x * 4 + wave;
    const int4  id = idx4[y];
    const float4 w = wgt4[y];
    const float* fb = x + (size_t)(y >> 12) * (NX_ * C_);

    const float4 f0 = *(const float4*)(fb + (size_t)id.x * C_ + lane * 4);
    const float4 f1 = *(const float4*)(fb + (size_t)id.y * C_ + lane * 4);
    const float4 f2 = *(const float4*)(fb + (size_t)id.z * C_ + lane * 4);

    ushort4 o;
    o.x = f2bf((w.x * f0.x + w.y * f1.x + w.z * f2.x) * w.w);
    o.y = f2bf((w.x * f0.y + w.y * f1.y + w.z * f2.y) * w.w);
    o.z = f2bf((w.x * f0.z + w.y * f1.z + w.z * f2.z) * w.w);
    o.w = f2bf((w.x * f0.w + w.y * f1.w + w.z * f2.w) * w.w);
    *(ushort4*)(h0 + (size_t)y * K1_ + lane * 4) = o;

    const float2 s2 = *(const float2*)(x_skip + (size_t)y * CS_ + lane * 2);
    ushort2 os; os.x = f2bf(s2.x); os.y = f2bf(s2.y);
    *(ushort2*)(h0 + (size_t)y * K1_ + C_ + lane * 2) = os;
}

// ---------------------------------------------------------------------------
// Kernel 3: cast + transpose weights to bf16 [N][K].
// ---------------------------------------------------------------------------
__global__ __launch_bounds__(256) void prep_w(
    const float* __restrict__ W1, const float* __restrict__ W2,
    unsigned short* __restrict__ W1t, unsigned short* __restrict__ W2t)
{
    int id = blockIdx.x * 256 + threadIdx.x;
    if (id < K1_ * H_) {
        int n = id / K1_, k = id - n * K1_;
        W1t[id] = f2bf(W1[(size_t)k * H_ + n]);
    }
    if (id < K2_ * H_) {
        int n = id >> 8, k = id & 255;
        W2t[id] = f2bf(W2[(size_t)k * H_ + n]);
    }
}

// ---------------------------------------------------------------------------
// Kernels 4/5: bf16 MFMA GEMM  out[M][256] = relu(A[M][K] * Bt[256][K]^T + b)
// BM=64, BN=256 (full N: A fetched once), BK=64, double-buffered LDS staged
// via global_load_lds(16B), XOR-swizzled (slot ^= row&7) on BOTH the global
// source and the ds_read so LDS dest stays linear (rule 21) and ds_read_b128
// is at the 2-way floor. 4 waves; wave w owns cols [w*64, w*64+64).
// mfma_f32_16x16x32_bf16 layouts per m89.
// ---------------------------------------------------------------------------
template<int K, int OUT_BF16>
__global__ __launch_bounds__(256) void gemm_bias_relu(
    const unsigned short* __restrict__ A,   // [M][K] bf16
    const unsigned short* __restrict__ Bt,  // [256][K] bf16
    const float* __restrict__ bias,         // [256]
    void* __restrict__ outp)                // [M][256] bf16 or f32
{
    __shared__ unsigned short As[2][64 * 64];    // 8 KiB per buf
    __shared__ unsigned short Bs[2][256 * 64];   // 32 KiB per buf

    const int tid  = threadIdx.x;
    const int lane = tid & 63;
    const int wave = tid >> 6;
    const int m0   = blockIdx.x * 64;
    const int r16  = lane & 15, qk = lane >> 4;

    floatx4 acc[4][4] = {};

    // stage K-step kt into buffer buf (LDS dest linear = tid*16 + inst*4KiB)
    auto stage = [&](int buf, int kt) {
        #pragma unroll
        for (int i = 0; i < 2; ++i) {
            const int row  = (tid >> 3) + i * 32;
            const int slot = (tid & 7) ^ (row & 7);
            gload_lds16(A + (size_t)(m0 + row) * K + kt + slot * 8,
                        &As[buf][row * 64 + (tid & 7) * 8]);
        }
        #pragma unroll
        for (int i = 0; i < 8; ++i) {
            const int row  = (tid >> 3) + i * 32;
            const int slot = (tid & 7) ^ (row & 7);
            gload_lds16(Bt + (size_t)row * K + kt + slot * 8,
                        &Bs[buf][row * 64 + (tid & 7) * 8]);
        }
    };

    auto compute = [&](int buf) {
        #pragma unroll
        for (int s = 0; s < 2; ++s) {
            short8 af[4], bf[4];
            #pragma unroll
            for (int m = 0; m < 4; ++m) {
                const int row  = m * 16 + r16;
                const int slot = (s * 4 + qk) ^ (r16 & 7);
                af[m] = *(const short8*)&As[buf][row * 64 + slot * 8];
            }
            #pragma unroll
            for (int n = 0; n < 4; ++n) {
                const int row  = wave * 64 + n * 16 + r16;
                const int slot = (s * 4 + qk) ^ (r16 & 7);
                bf[n] = *(const short8*)&Bs[buf][row * 64 + slot * 8];
            }
            #pragma unroll
            for (int m = 0; m < 4; ++m)
                #pragma unroll
                for (int n = 0; n < 4; ++n)
                    acc[m][n] = __builtin_amdgcn_mfma_f32_16x16x32_bf16(
                        af[m], bf[n], acc[m][n], 0, 0, 0);
        }
    };

    stage(0, 0);
    __syncthreads();                     // drains vmcnt(0): buf0 ready
    int cur = 0;
    constexpr int NT = K / 64;
    #pragma unroll
    for (int t = 1; t < NT; ++t) {
        stage(cur ^ 1, t * 64);          // next tile in flight during compute
        compute(cur);
        __syncthreads();                 // drain stage + all waves done reading
        cur ^= 1;
    }
    compute(cur);

    #pragma unroll
    for (int n = 0; n < 4; ++n) {
        const int gc = wave * 64 + n * 16 + r16;
        const float bv = bias[gc];
        #pragma unroll
        for (int m = 0; m < 4; ++m) {
            #pragma unroll
            for (int r = 0; r < 4; ++r) {
                const int gr = m0 + m * 16 + qk * 4 + r;
                float v = fmaxf(acc[m][n][r] + bv, 0.0f);
                if (OUT_BF16)
                    ((unsigned short*)outp)[(size_t)gr * H_ + gc] = f2bf(v);
                else
                    ((float*)outp)[(size_t)gr * H_ + gc] = v;
            }
        }
    }
}

// ---------------------------------------------------------------------------
extern "C" void kernel_launch(void* const* d_in, const int* in_sizes, int n_in,
                              void* d_out, int out_size, void* d_ws, size_t ws_size,
                              hipStream_t stream)
{
    const float* x        = (const float*)d_in[0];
    const float* pos      = (const float*)d_in[1];
    const float* x_skip   = (const float*)d_in[3];
    const float* pos_skip = (const float*)d_in[4];
    const float* W1       = (const float*)d_in[6];
    const float* b1       = (const float*)d_in[7];
    const float* W2       = (const float*)d_in[8];
    const float* b2       = (const float*)d_in[9];

    char* ws = (char*)d_ws;
    unsigned short* h0  = (unsigned short*)(ws);                    // 48 MiB
    unsigned short* h1  = (unsigned short*)(ws + 50331648);         // 32 MiB
    unsigned short* W1t = (unsigned short*)(ws + 83886080);         // 192 KiB
    unsigned short* W2t = (unsigned short*)(ws + 84082688);         // 128 KiB
    int4*           idx4 = (int4*)(ws + 84213760);                  // 1 MiB
    float4*         wgt4 = (float4*)(ws + 85262336);                // 1 MiB

    hipLaunchKernelGGL(knn_select, dim3(M_ / 256), dim3(512), 0, stream,
                       pos, pos_skip, idx4, wgt4);
    hipLaunchKernelGGL(gather_concat, dim3(M_ / 4), dim3(256), 0, stream,
                       x, x_skip, idx4, wgt4, h0);
    hipLaunchKernelGGL(prep_w, dim3((K1_ * H_ + 255) / 256), dim3(256), 0, stream,
                       W1, W2, W1t, W2t);
    hipLaunchKernelGGL((gemm_bias_relu<K1_, 1>), dim3(M_ / 64), dim3(256),
                       0, stream, h0, W1t, b1, h1);
    hipLaunchKernelGGL((gemm_bias_relu<K2_, 0>), dim3(M_ / 64), dim3(256),
                       0, stream, h1, W2t, b2, (float*)d_out);
}

// Round 5
// 214.297 us; speedup vs baseline: 1.0923x; 1.0742x over previous
//
#include <hip/hip_runtime.h>
#include <hip/hip_bf16.h>

// Problem constants (match reference)
#define B_  16
#define NX_ 1024
#define NY_ 4096
#define C_  256
#define CS_ 128
#define H_  256
#define M_  (B_ * NY_)     // 65536 rows through the MLP
#define K1_ (C_ + CS_)     // 384
#define K2_ (H_)           // 256

using short8  = __attribute__((ext_vector_type(8))) short;
using floatx4 = __attribute__((ext_vector_type(4))) float;

__device__ __forceinline__ unsigned short f2bf(float f) {
    unsigned int u = __float_as_uint(f);
    unsigned int r = (u + 0x7fffu + ((u >> 16) & 1u)) >> 16;
    return (unsigned short)r;
}

// global -> LDS async 16B copy (dest must be linear: wave base + lane*16)
typedef const __attribute__((address_space(1))) void gas_t;
typedef __attribute__((address_space(3))) void las_t;
__device__ __forceinline__ void gload_lds16(const void* g, void* l) {
    __builtin_amdgcn_global_load_lds((gas_t*)g, (las_t*)l, 16, 0, 0);
}

// ---------------------------------------------------------------------------
// Kernel 1: KNN select. One point per 4 threads: thread quarter q scans
// coarse points [q*256,(q+1)*256), merged via LDS (3-list merge tree, lower
// index wins ties => matches lax.top_k). 64 points/block, 256 threads,
// grid 1024 blocks (4 blocks/CU -> ~50% occupancy vs 20% before).
// Distance formula replicates reference Gram trick with _rn ops.
// ---------------------------------------------------------------------------
__global__ __launch_bounds__(256) void knn_select(
    const float* __restrict__ pos, const float* __restrict__ pos_skip,
    int4* __restrict__ idx4, float4* __restrict__ wgt4)
{
    __shared__ float4 sp[NX_];           // 16 KiB (px,py,pz,|p|^2)
    __shared__ float  md[3][3][64];      // [quarter-1][rank][point]
    __shared__ int    mi[3][3][64];

    const int tid = threadIdx.x;
    const int q   = tid >> 6;            // scan quarter 0..3 (= wave id)
    const int p   = tid & 63;            // point slot (= lane)
    const int y   = blockIdx.x * 64 + p;
    const int b   = y >> 12;             // cloud (4096 fine pts per cloud)

    for (int j = tid; j < NX_; j += 256) {
        const float* pp = pos + (size_t)(b * NX_ + j) * 3;
        float px = pp[0], py = pp[1], pz = pp[2];
        float pn = __fadd_rn(__fadd_rn(__fmul_rn(px, px), __fmul_rn(py, py)),
                             __fmul_rn(pz, pz));
        sp[j] = make_float4(px, py, pz, pn);
    }
    __syncthreads();

    const float* qp = pos_skip + (size_t)y * 3;
    const float qx = qp[0], qy = qp[1], qz = qp[2];
    const float qn = __fadd_rn(__fadd_rn(__fmul_rn(qx, qx), __fmul_rn(qy, qy)),
                               __fmul_rn(qz, qz));

    // per-thread top-3 over this quarter (ascending d2; strict < keeps the
    // earliest index on ties since j increases)
    float d0 = 3.4e38f, d1 = 3.4e38f, d2 = 3.4e38f;
    int   n0 = 0x7fffffff, n1 = 0x7fffffff, n2 = 0x7fffffff;
    const int j0 = q * 256;
    #pragma unroll 8
    for (int t = 0; t < 256; ++t) {
        const int j = j0 + t;
        const float4 pv = sp[j];         // broadcast within wave (lane-uniform)
        float dot = __fadd_rn(__fadd_rn(__fmul_rn(qx, pv.x),
                                        __fmul_rn(qy, pv.y)),
                              __fmul_rn(qz, pv.z));
        float dd = __fsub_rn(__fadd_rn(qn, pv.w), __fmul_rn(2.0f, dot));
        if (dd < d2) {
            if (dd < d1) {
                d2 = d1; n2 = n1;
                if (dd < d0) { d1 = d0; n1 = n0; d0 = dd; n0 = j; }
                else         { d1 = dd; n1 = j; }
            } else { d2 = dd; n2 = j; }
        }
    }

    if (q != 0) {
        md[q - 1][0][p] = d0; md[q - 1][1][p] = d1; md[q - 1][2][p] = d2;
        mi[q - 1][0][p] = n0; mi[q - 1][1][p] = n1; mi[q - 1][2][p] = n2;
    }
    __syncthreads();

    if (q == 0) {
        // merge quarters 1..3 into accumulated list; acc has lower j-range so
        // <= keeps the lower index on equal distances (lax.top_k semantics)
        #pragma unroll
        for (int m = 0; m < 3; ++m) {
            const float b0 = md[m][0][p], b1 = md[m][1][p], b2 = md[m][2][p];
            const int  ib0 = mi[m][0][p], ib1 = mi[m][1][p], ib2 = mi[m][2][p];
            const float a0 = d0, a1 = d1, a2 = d2;
            const int  ia0 = n0, ia1 = n1, ia2 = n2;
            if (a0 <= b0) {
                d0 = a0; n0 = ia0;
                if (a1 <= b0) { d1 = a1; n1 = ia1;
                    bool c = (a2 <= b0); d2 = c ? a2 : b0; n2 = c ? ia2 : ib0; }
                else          { d1 = b0; n1 = ib0;
                    bool c = (a1 <= b1); d2 = c ? a1 : b1; n2 = c ? ia1 : ib1; }
            } else {
                d0 = b0; n0 = ib0;
                if (a0 <= b1) { d1 = a0; n1 = ia0;
                    bool c = (a1 <= b1); d2 = c ? a1 : b1; n2 = c ? ia1 : ib1; }
                else          { d1 = b1; n1 = ib1;
                    bool c = (a0 <= b2); d2 = c ? a0 : b2; n2 = c ? ia0 : ib2; }
            }
        }
        const float w0 = 1.0f / (sqrtf(fmaxf(d0, 0.0f)) + 1e-8f);
        const float w1 = 1.0f / (sqrtf(fmaxf(d1, 0.0f)) + 1e-8f);
        const float w2 = 1.0f / (sqrtf(fmaxf(d2, 0.0f)) + 1e-8f);
        const float inv_den = 1.0f / (w0 + w1 + w2 + 1e-8f);
        idx4[y] = make_int4(n0, n1, n2, 0);
        wgt4[y] = make_float4(w0, w1, w2, inv_den);
    }
}

// ---------------------------------------------------------------------------
// Kernel 2: gather 3 feature rows per point, blend, concat x_skip -> h0 bf16.
// One wave per point, coalesced float4 gathers (x is L2-resident per cloud).
// ---------------------------------------------------------------------------
__global__ __launch_bounds__(256) void gather_concat(
    const float* __restrict__ x, const float* __restrict__ x_skip,
    const int4* __restrict__ idx4, const float4* __restrict__ wgt4,
    unsigned short* __restrict__ h0)
{
    const int wave = threadIdx.x >> 6, lane = threadIdx.x & 63;
    const int y = blockIdx.x * 4 + wave;
    const int4  id = idx4[y];
    const float4 w = wgt4[y];
    const float* fb = x + (size_t)(y >> 12) * (NX_ * C_);

    const float4 f0 = *(const float4*)(fb + (size_t)id.x * C_ + lane * 4);
    const float4 f1 = *(const float4*)(fb + (size_t)id.y * C_ + lane * 4);
    const float4 f2 = *(const float4*)(fb + (size_t)id.z * C_ + lane * 4);

    ushort4 o;
    o.x = f2bf((w.x * f0.x + w.y * f1.x + w.z * f2.x) * w.w);
    o.y = f2bf((w.x * f0.y + w.y * f1.y + w.z * f2.y) * w.w);
    o.z = f2bf((w.x * f0.z + w.y * f1.z + w.z * f2.z) * w.w);
    o.w = f2bf((w.x * f0.w + w.y * f1.w + w.z * f2.w) * w.w);
    *(ushort4*)(h0 + (size_t)y * K1_ + lane * 4) = o;

    const float2 s2 = *(const float2*)(x_skip + (size_t)y * CS_ + lane * 2);
    ushort2 os; os.x = f2bf(s2.x); os.y = f2bf(s2.y);
    *(ushort2*)(h0 + (size_t)y * K1_ + C_ + lane * 2) = os;
}

// ---------------------------------------------------------------------------
// Kernel 3: cast + transpose weights to bf16 [N][K].
// ---------------------------------------------------------------------------
__global__ __launch_bounds__(256) void prep_w(
    const float* __restrict__ W1, const float* __restrict__ W2,
    unsigned short* __restrict__ W1t, unsigned short* __restrict__ W2t)
{
    int id = blockIdx.x * 256 + threadIdx.x;
    if (id < K1_ * H_) {
        int n = id / K1_, k = id - n * K1_;
        W1t[id] = f2bf(W1[(size_t)k * H_ + n]);
    }
    if (id < K2_ * H_) {
        int n = id >> 8, k = id & 255;
        W2t[id] = f2bf(W2[(size_t)k * H_ + n]);
    }
}

// ---------------------------------------------------------------------------
// Kernels 4/5: bf16 MFMA GEMM  out[M][256] = relu(A[M][K] * Bt[256][K]^T + b)
// BM=64, BN=256 (full N: A fetched once), BK=64, double-buffered LDS staged
// via global_load_lds(16B), XOR-swizzled (slot ^= row&7) on BOTH the global
// source and the ds_read so LDS dest stays linear (rule 21) and ds_read_b128
// is at the 2-way floor. 4 waves; wave w owns cols [w*64, w*64+64).
// mfma_f32_16x16x32_bf16 layouts per m89.
// ---------------------------------------------------------------------------
template<int K, int OUT_BF16>
__global__ __launch_bounds__(256) void gemm_bias_relu(
    const unsigned short* __restrict__ A,   // [M][K] bf16
    const unsigned short* __restrict__ Bt,  // [256][K] bf16
    const float* __restrict__ bias,         // [256]
    void* __restrict__ outp)                // [M][256] bf16 or f32
{
    __shared__ unsigned short As[2][64 * 64];    // 8 KiB per buf
    __shared__ unsigned short Bs[2][256 * 64];   // 32 KiB per buf

    const int tid  = threadIdx.x;
    const int lane = tid & 63;
    const int wave = tid >> 6;
    const int m0   = blockIdx.x * 64;
    const int r16  = lane & 15, qk = lane >> 4;

    floatx4 acc[4][4] = {};

    // stage K-step kt into buffer buf (LDS dest linear = tid*16 + inst*4KiB)
    auto stage = [&](int buf, int kt) {
        #pragma unroll
        for (int i = 0; i < 2; ++i) {
            const int row  = (tid >> 3) + i * 32;
            const int slot = (tid & 7) ^ (row & 7);
            gload_lds16(A + (size_t)(m0 + row) * K + kt + slot * 8,
                        &As[buf][row * 64 + (tid & 7) * 8]);
        }
        #pragma unroll
        for (int i = 0; i < 8; ++i) {
            const int row  = (tid >> 3) + i * 32;
            const int slot = (tid & 7) ^ (row & 7);
            gload_lds16(Bt + (size_t)row * K + kt + slot * 8,
                        &Bs[buf][row * 64 + (tid & 7) * 8]);
        }
    };

    auto compute = [&](int buf) {
        #pragma unroll
        for (int s = 0; s < 2; ++s) {
            short8 af[4], bf[4];
            #pragma unroll
            for (int m = 0; m < 4; ++m) {
                const int row  = m * 16 + r16;
                const int slot = (s * 4 + qk) ^ (r16 & 7);
                af[m] = *(const short8*)&As[buf][row * 64 + slot * 8];
            }
            #pragma unroll
            for (int n = 0; n < 4; ++n) {
                const int row  = wave * 64 + n * 16 + r16;
                const int slot = (s * 4 + qk) ^ (r16 & 7);
                bf[n] = *(const short8*)&Bs[buf][row * 64 + slot * 8];
            }
            #pragma unroll
            for (int m = 0; m < 4; ++m)
                #pragma unroll
                for (int n = 0; n < 4; ++n)
                    acc[m][n] = __builtin_amdgcn_mfma_f32_16x16x32_bf16(
                        af[m], bf[n], acc[m][n], 0, 0, 0);
        }
    };

    stage(0, 0);
    __syncthreads();                     // drains vmcnt(0): buf0 ready
    int cur = 0;
    constexpr int NT = K / 64;
    #pragma unroll
    for (int t = 1; t < NT; ++t) {
        stage(cur ^ 1, t * 64);          // next tile in flight during compute
        compute(cur);
        __syncthreads();                 // drain stage + all waves done reading
        cur ^= 1;
    }
    compute(cur);

    #pragma unroll
    for (int n = 0; n < 4; ++n) {
        const int gc = wave * 64 + n * 16 + r16;
        const float bv = bias[gc];
        #pragma unroll
        for (int m = 0; m < 4; ++m) {
            #pragma unroll
            for (int r = 0; r < 4; ++r) {
                const int gr = m0 + m * 16 + qk * 4 + r;
                float v = fmaxf(acc[m][n][r] + bv, 0.0f);
                if (OUT_BF16)
                    ((unsigned short*)outp)[(size_t)gr * H_ + gc] = f2bf(v);
                else
                    ((float*)outp)[(size_t)gr * H_ + gc] = v;
            }
        }
    }
}

// ---------------------------------------------------------------------------
extern "C" void kernel_launch(void* const* d_in, const int* in_sizes, int n_in,
                              void* d_out, int out_size, void* d_ws, size_t ws_size,
                              hipStream_t stream)
{
    const float* x        = (const float*)d_in[0];
    const float* pos      = (const float*)d_in[1];
    const float* x_skip   = (const float*)d_in[3];
    const float* pos_skip = (const float*)d_in[4];
    const float* W1       = (const float*)d_in[6];
    const float* b1       = (const float*)d_in[7];
    const float* W2       = (const float*)d_in[8];
    const float* b2       = (const float*)d_in[9];

    char* ws = (char*)d_ws;
    unsigned short* h0  = (unsigned short*)(ws);                    // 48 MiB
    unsigned short* h1  = (unsigned short*)(ws + 50331648);         // 32 MiB
    unsigned short* W1t = (unsigned short*)(ws + 83886080);         // 192 KiB
    unsigned short* W2t = (unsigned short*)(ws + 84082688);         // 128 KiB
    int4*           idx4 = (int4*)(ws + 84213760);                  // 1 MiB
    float4*         wgt4 = (float4*)(ws + 85262336);                // 1 MiB

    hipLaunchKernelGGL(knn_select, dim3(M_ / 64), dim3(256), 0, stream,
                       pos, pos_skip, idx4, wgt4);
    hipLaunchKernelGGL(gather_concat, dim3(M_ / 4), dim3(256), 0, stream,
                       x, x_skip, idx4, wgt4, h0);
    hipLaunchKernelGGL(prep_w, dim3((K1_ * H_ + 255) / 256), dim3(256), 0, stream,
                       W1, W2, W1t, W2t);
    hipLaunchKernelGGL((gemm_bias_relu<K1_, 1>), dim3(M_ / 64), dim3(256),
                       0, stream, h0, W1t, b1, h1);
    hipLaunchKernelGGL((gemm_bias_relu<K2_, 0>), dim3(M_ / 64), dim3(256),
                       0, stream, h1, W2t, b2, (float*)d_out);
}

// Round 6
// 206.835 us; speedup vs baseline: 1.1317x; 1.0361x over previous
//
#include <hip/hip_runtime.h>
#include <hip/hip_bf16.h>

// Problem constants (match reference)
#define B_  16
#define NX_ 1024
#define NY_ 4096
#define C_  256
#define CS_ 128
#define H_  256
#define M_  (B_ * NY_)     // 65536 rows through the MLP
#define K1_ (C_ + CS_)     // 384
#define K2_ (H_)           // 256

using short8  = __attribute__((ext_vector_type(8))) short;
using floatx4 = __attribute__((ext_vector_type(4))) float;

__device__ __forceinline__ unsigned short f2bf(float f) {
    unsigned int u = __float_as_uint(f);
    unsigned int r = (u + 0x7fffu + ((u >> 16) & 1u)) >> 16;
    return (unsigned short)r;
}

// global -> LDS async 16B copy (dest must be linear: wave base + lane*16)
typedef const __attribute__((address_space(1))) void gas_t;
typedef __attribute__((address_space(3))) void las_t;
__device__ __forceinline__ void gload_lds16(const void* g, void* l) {
    __builtin_amdgcn_global_load_lds((gas_t*)g, (las_t*)l, 16, 0, 0);
}

// ---------------------------------------------------------------------------
// Kernel 1: KNN select. 8 threads per point (each scans 128 coarse pts),
// 32 points/block, 256 threads, grid 2048 (LDS 21.3KiB -> 7 blocks/CU,
// ~28 waves/CU vs 33% before). Same _rn Gram-trick arithmetic + strict-<
// insertion + ordered merge tree (lower j range preferred on ties) that
// matches lax.top_k and has passed refcheck twice.
// ---------------------------------------------------------------------------
__global__ __launch_bounds__(256) void knn_select(
    const float* __restrict__ pos, const float* __restrict__ pos_skip,
    int4* __restrict__ idx4, float4* __restrict__ wgt4)
{
    __shared__ float4 sp[NX_];           // 16 KiB (px,py,pz,|p|^2)
    __shared__ float  md[7][3][32];      // [eighth-1][rank][point]
    __shared__ int    mi[7][3][32];

    const int tid = threadIdx.x;
    const int e   = tid >> 5;            // scan eighth 0..7
    const int p   = tid & 31;            // point slot
    const int y   = blockIdx.x * 32 + p;
    const int b   = y >> 12;             // cloud (4096 fine pts per cloud)

    for (int j = tid; j < NX_; j += 256) {
        const float* pp = pos + (size_t)(b * NX_ + j) * 3;
        float px = pp[0], py = pp[1], pz = pp[2];
        float pn = __fadd_rn(__fadd_rn(__fmul_rn(px, px), __fmul_rn(py, py)),
                             __fmul_rn(pz, pz));
        sp[j] = make_float4(px, py, pz, pn);
    }
    __syncthreads();

    const float* qp = pos_skip + (size_t)y * 3;
    const float qx = qp[0], qy = qp[1], qz = qp[2];
    const float qn = __fadd_rn(__fadd_rn(__fmul_rn(qx, qx), __fmul_rn(qy, qy)),
                               __fmul_rn(qz, qz));

    float d0 = 3.4e38f, d1 = 3.4e38f, d2 = 3.4e38f;
    int   n0 = 0x7fffffff, n1 = 0x7fffffff, n2 = 0x7fffffff;
    const int j0 = e * 128;
    #pragma unroll 8
    for (int t = 0; t < 128; ++t) {
        const int j = j0 + t;
        const float4 pv = sp[j];
        float dot = __fadd_rn(__fadd_rn(__fmul_rn(qx, pv.x),
                                        __fmul_rn(qy, pv.y)),
                              __fmul_rn(qz, pv.z));
        float dd = __fsub_rn(__fadd_rn(qn, pv.w), __fmul_rn(2.0f, dot));
        if (dd < d2) {
            if (dd < d1) {
                d2 = d1; n2 = n1;
                if (dd < d0) { d1 = d0; n1 = n0; d0 = dd; n0 = j; }
                else         { d1 = dd; n1 = j; }
            } else { d2 = dd; n2 = j; }
        }
    }

    if (e != 0) {
        md[e - 1][0][p] = d0; md[e - 1][1][p] = d1; md[e - 1][2][p] = d2;
        mi[e - 1][0][p] = n0; mi[e - 1][1][p] = n1; mi[e - 1][2][p] = n2;
    }
    __syncthreads();

    if (e == 0) {
        // merge eighths 1..7 in ascending j order; acc list has lower j range
        // so <= keeps the lower index on equal distances (lax.top_k)
        #pragma unroll
        for (int m = 0; m < 7; ++m) {
            const float b0 = md[m][0][p], b1 = md[m][1][p], b2 = md[m][2][p];
            const int  ib0 = mi[m][0][p], ib1 = mi[m][1][p], ib2 = mi[m][2][p];
            const float a0 = d0, a1 = d1, a2 = d2;
            const int  ia0 = n0, ia1 = n1, ia2 = n2;
            if (a0 <= b0) {
                d0 = a0; n0 = ia0;
                if (a1 <= b0) { d1 = a1; n1 = ia1;
                    bool c = (a2 <= b0); d2 = c ? a2 : b0; n2 = c ? ia2 : ib0; }
                else          { d1 = b0; n1 = ib0;
                    bool c = (a1 <= b1); d2 = c ? a1 : b1; n2 = c ? ia1 : ib1; }
            } else {
                d0 = b0; n0 = ib0;
                if (a0 <= b1) { d1 = a0; n1 = ia0;
                    bool c = (a1 <= b1); d2 = c ? a1 : b1; n2 = c ? ia1 : ib1; }
                else          { d1 = b1; n1 = ib1;
                    bool c = (a0 <= b2); d2 = c ? a0 : b2; n2 = c ? ia0 : ib2; }
            }
        }
        const float w0 = 1.0f / (sqrtf(fmaxf(d0, 0.0f)) + 1e-8f);
        const float w1 = 1.0f / (sqrtf(fmaxf(d1, 0.0f)) + 1e-8f);
        const float w2 = 1.0f / (sqrtf(fmaxf(d2, 0.0f)) + 1e-8f);
        const float inv_den = 1.0f / (w0 + w1 + w2 + 1e-8f);
        idx4[y] = make_int4(n0, n1, n2, 0);
        wgt4[y] = make_float4(w0, w1, w2, inv_den);
    }
}

// ---------------------------------------------------------------------------
// Kernel 2: cast + transpose weights to bf16 [N][K].
// ---------------------------------------------------------------------------
__global__ __launch_bounds__(256) void prep_w(
    const float* __restrict__ W1, const float* __restrict__ W2,
    unsigned short* __restrict__ W1t, unsigned short* __restrict__ W2t)
{
    int id = blockIdx.x * 256 + threadIdx.x;
    if (id < K1_ * H_) {
        int n = id / K1_, k = id - n * K1_;
        W1t[id] = f2bf(W1[(size_t)k * H_ + n]);
    }
    if (id < K2_ * H_) {
        int n = id >> 8, k = id & 255;
        W2t[id] = f2bf(W2[(size_t)k * H_ + n]);
    }
}

// ---------------------------------------------------------------------------
// Kernel 3: FUSED gather+interp+concat + GEMM1.
// h1[M][256] = relu(concat(interp, x_skip)[M][384] @ W1 + b1)
// Each block owns 64 rows (exact partition -> interp computed exactly once).
// Prologue: wave w gathers rows w*16..w*16+15 (full-wave coalesced float4
// gathers from x, blend, + x_skip), ds_writes bf16 into As_full[6][64][64]
// using the SAME XOR-slot swizzle the MFMA ds_reads use (write side = read
// side, rule 21). Bs single-buffered (B is L2-resident; 2 blocks/CU overlap
// the stage stall). LDS = 48 + 32 = 80 KiB.
// ---------------------------------------------------------------------------
__global__ __launch_bounds__(256) void gemm1_fused(
    const float* __restrict__ x, const float* __restrict__ x_skip,
    const int4* __restrict__ idx4, const float4* __restrict__ wgt4,
    const unsigned short* __restrict__ Bt,   // W1t [256][384] bf16
    const float* __restrict__ bias,          // b1
    unsigned short* __restrict__ outp)       // h1 [M][256] bf16
{
    __shared__ unsigned short As_full[6 * 64 * 64];   // 48 KiB, swizzled slots
    __shared__ unsigned short Bs[256 * 64];           // 32 KiB

    const int tid  = threadIdx.x;
    const int lane = tid & 63;
    const int wave = tid >> 6;
    const int m0   = blockIdx.x * 64;
    const int r16  = lane & 15, qk = lane >> 4;

    auto stageB = [&](int kt) {
        #pragma unroll
        for (int i = 0; i < 8; ++i) {
            const int row  = (tid >> 3) + i * 32;
            const int slot = (tid & 7) ^ (row & 7);
            gload_lds16(Bt + (size_t)row * K1_ + kt + slot * 8,
                        &Bs[row * 64 + (tid & 7) * 8]);
        }
    };

    stageB(0);

    // ---- fused interp prologue: wave w -> rows [w*16, w*16+16) ----
    {
        const int ks  = lane >> 4;            // K-step of interp cols lane*4
        const int cs  = (lane * 4) & 63;      // col within step
        const int sl  = cs >> 3;              // 8-col slot
        const int of  = cs & 7;               // 0 or 4
        const int ks2  = 4 + (lane >> 5);     // K-step of skip cols 256+lane*2
        const int cs2  = (lane * 2) & 63;
        const int sl2  = cs2 >> 3;
        const int of2  = cs2 & 7;
        #pragma unroll 4
        for (int i = 0; i < 16; ++i) {
            const int r  = wave * 16 + i;
            const int gr = m0 + r;
            const int4   id = idx4[gr];
            const float4 wt = wgt4[gr];
            const float* fb = x + (size_t)(gr >> 12) * (NX_ * C_);
            const float4 f0 = *(const float4*)(fb + (size_t)id.x * C_ + lane * 4);
            const float4 f1 = *(const float4*)(fb + (size_t)id.y * C_ + lane * 4);
            const float4 f2 = *(const float4*)(fb + (size_t)id.z * C_ + lane * 4);
            ushort4 o;
            o.x = f2bf((wt.x * f0.x + wt.y * f1.x + wt.z * f2.x) * wt.w);
            o.y = f2bf((wt.x * f0.y + wt.y * f1.y + wt.z * f2.y) * wt.w);
            o.z = f2bf((wt.x * f0.z + wt.y * f1.z + wt.z * f2.z) * wt.w);
            o.w = f2bf((wt.x * f0.w + wt.y * f1.w + wt.z * f2.w) * wt.w);
            *(ushort4*)&As_full[ks * 4096 + r * 64 + (sl ^ (r & 7)) * 8 + of] = o;

            const float2 s2 = *(const float2*)(x_skip + (size_t)gr * CS_ + lane * 2);
            ushort2 os; os.x = f2bf(s2.x); os.y = f2bf(s2.y);
            *(ushort2*)&As_full[ks2 * 4096 + r * 64 + (sl2 ^ (r & 7)) * 8 + of2] = os;
        }
    }
    __syncthreads();        // drains gload vmcnt + prologue ds_writes

    floatx4 acc[4][4] = {};

    #pragma unroll
    for (int t = 0; t < 6; ++t) {
        const unsigned short* At = As_full + t * 4096;
        #pragma unroll
        for (int s = 0; s < 2; ++s) {
            short8 af[4], bf[4];
            #pragma unroll
            for (int m = 0; m < 4; ++m) {
                const int row  = m * 16 + r16;
                const int slot = (s * 4 + qk) ^ (r16 & 7);
                af[m] = *(const short8*)&At[row * 64 + slot * 8];
            }
            #pragma unroll
            for (int n = 0; n < 4; ++n) {
                const int row  = wave * 64 + n * 16 + r16;
                const int slot = (s * 4 + qk) ^ (r16 & 7);
                bf[n] = *(const short8*)&Bs[row * 64 + slot * 8];
            }
            #pragma unroll
            for (int m = 0; m < 4; ++m)
                #pragma unroll
                for (int n = 0; n < 4; ++n)
                    acc[m][n] = __builtin_amdgcn_mfma_f32_16x16x32_bf16(
                        af[m], bf[n], acc[m][n], 0, 0, 0);
        }
        if (t < 5) {
            __syncthreads();             // all waves done reading Bs
            stageB((t + 1) * 64);
            __syncthreads();             // Bs[t+1] ready
        }
    }

    #pragma unroll
    for (int n = 0; n < 4; ++n) {
        const int gc = wave * 64 + n * 16 + r16;
        const float bv = bias[gc];
        #pragma unroll
        for (int m = 0; m < 4; ++m) {
            #pragma unroll
            for (int r = 0; r < 4; ++r) {
                const int gr = m0 + m * 16 + qk * 4 + r;
                float v = fmaxf(acc[m][n][r] + bv, 0.0f);
                outp[(size_t)gr * H_ + gc] = f2bf(v);
            }
        }
    }
}

// ---------------------------------------------------------------------------
// Kernel 4: GEMM2  out[M][256] = relu(h1[M][256] @ W2 + b2), fp32 out.
// BM=64, BN=256, BK=64, dbuf LDS via global_load_lds(16B), XOR swizzle on
// both source and ds_read (rule 21). Same structure as round 5 (passed).
// ---------------------------------------------------------------------------
__global__ __launch_bounds__(256) void gemm2_bias_relu(
    const unsigned short* __restrict__ A,   // h1 [M][256] bf16
    const unsigned short* __restrict__ Bt,  // W2t [256][256] bf16
    const float* __restrict__ bias,         // b2
    float* __restrict__ outp)               // [M][256] f32
{
    __shared__ unsigned short As[2][64 * 64];    // 8 KiB per buf
    __shared__ unsigned short Bs[2][256 * 64];   // 32 KiB per buf

    const int tid  = threadIdx.x;
    const int lane = tid & 63;
    const int wave = tid >> 6;
    const int m0   = blockIdx.x * 64;
    const int r16  = lane & 15, qk = lane >> 4;

    floatx4 acc[4][4] = {};

    auto stage = [&](int buf, int kt) {
        #pragma unroll
        for (int i = 0; i < 2; ++i) {
            const int row  = (tid >> 3) + i * 32;
            const int slot = (tid & 7) ^ (row & 7);
            gload_lds16(A + (size_t)(m0 + row) * K2_ + kt + slot * 8,
                        &As[buf][row * 64 + (tid & 7) * 8]);
        }
        #pragma unroll
        for (int i = 0; i < 8; ++i) {
            const int row  = (tid >> 3) + i * 32;
            const int slot = (tid & 7) ^ (row & 7);
            gload_lds16(Bt + (size_t)row * K2_ + kt + slot * 8,
                        &Bs[buf][row * 64 + (tid & 7) * 8]);
        }
    };

    auto compute = [&](int buf) {
        #pragma unroll
        for (int s = 0; s < 2; ++s) {
            short8 af[4], bf[4];
            #pragma unroll
            for (int m = 0; m < 4; ++m) {
                const int row  = m * 16 + r16;
                const int slot = (s * 4 + qk) ^ (r16 & 7);
                af[m] = *(const short8*)&As[buf][row * 64 + slot * 8];
            }
            #pragma unroll
            for (int n = 0; n < 4; ++n) {
                const int row  = wave * 64 + n * 16 + r16;
                const int slot = (s * 4 + qk) ^ (r16 & 7);
                bf[n] = *(const short8*)&Bs[buf][row * 64 + slot * 8];
            }
            #pragma unroll
            for (int m = 0; m < 4; ++m)
                #pragma unroll
                for (int n = 0; n < 4; ++n)
                    acc[m][n] = __builtin_amdgcn_mfma_f32_16x16x32_bf16(
                        af[m], bf[n], acc[m][n], 0, 0, 0);
        }
    };

    stage(0, 0);
    __syncthreads();
    int cur = 0;
    #pragma unroll
    for (int t = 1; t < 4; ++t) {
        stage(cur ^ 1, t * 64);
        compute(cur);
        __syncthreads();
        cur ^= 1;
    }
    compute(cur);

    #pragma unroll
    for (int n = 0; n < 4; ++n) {
        const int gc = wave * 64 + n * 16 + r16;
        const float bv = bias[gc];
        #pragma unroll
        for (int m = 0; m < 4; ++m) {
            #pragma unroll
            for (int r = 0; r < 4; ++r) {
                const int gr = m0 + m * 16 + qk * 4 + r;
                outp[(size_t)gr * H_ + gc] = fmaxf(acc[m][n][r] + bv, 0.0f);
            }
        }
    }
}

// ---------------------------------------------------------------------------
extern "C" void kernel_launch(void* const* d_in, const int* in_sizes, int n_in,
                              void* d_out, int out_size, void* d_ws, size_t ws_size,
                              hipStream_t stream)
{
    const float* x        = (const float*)d_in[0];
    const float* pos      = (const float*)d_in[1];
    const float* x_skip   = (const float*)d_in[3];
    const float* pos_skip = (const float*)d_in[4];
    const float* W1       = (const float*)d_in[6];
    const float* b1       = (const float*)d_in[7];
    const float* W2       = (const float*)d_in[8];
    const float* b2       = (const float*)d_in[9];

    char* ws = (char*)d_ws;
    unsigned short* h1  = (unsigned short*)(ws);                    // 32 MiB
    unsigned short* W1t = (unsigned short*)(ws + 33554432);         // 192 KiB
    unsigned short* W2t = (unsigned short*)(ws + 33751040);         // 128 KiB
    int4*           idx4 = (int4*)(ws + 33882112);                  // 1 MiB
    float4*         wgt4 = (float4*)(ws + 34930688);                // 1 MiB

    hipLaunchKernelGGL(knn_select, dim3(M_ / 32), dim3(256), 0, stream,
                       pos, pos_skip, idx4, wgt4);
    hipLaunchKernelGGL(prep_w, dim3((K1_ * H_ + 255) / 256), dim3(256), 0, stream,
                       W1, W2, W1t, W2t);
    hipLaunchKernelGGL(gemm1_fused, dim3(M_ / 64), dim3(256), 0, stream,
                       x, x_skip, idx4, wgt4, W1t, b1, h1);
    hipLaunchKernelGGL(gemm2_bias_relu, dim3(M_ / 64), dim3(256), 0, stream,
                       h1, W2t, b2, (float*)d_out);
}

// Round 7
// 205.498 us; speedup vs baseline: 1.1391x; 1.0065x over previous
//
#include <hip/hip_runtime.h>
#include <hip/hip_bf16.h>

// Problem constants (match reference)
#define B_  16
#define NX_ 1024
#define NY_ 4096
#define C_  256
#define CS_ 128
#define H_  256
#define M_  (B_ * NY_)     // 65536 rows through the MLP
#define K1_ (C_ + CS_)     // 384
#define K2_ (H_)           // 256

using short8  = __attribute__((ext_vector_type(8))) short;
using floatx4 = __attribute__((ext_vector_type(4))) float;

__device__ __forceinline__ unsigned short f2bf(float f) {
    unsigned int u = __float_as_uint(f);
    unsigned int r = (u + 0x7fffu + ((u >> 16) & 1u)) >> 16;
    return (unsigned short)r;
}

// global -> LDS async 16B copy (dest must be linear: wave base + lane*16)
typedef const __attribute__((address_space(1))) void gas_t;
typedef __attribute__((address_space(3))) void las_t;
__device__ __forceinline__ void gload_lds16(const void* g, void* l) {
    __builtin_amdgcn_global_load_lds((gas_t*)g, (las_t*)l, 16, 0, 0);
}

// ---------------------------------------------------------------------------
// Kernel 1: KNN select (+ folded weight transpose/cast).
// 8 threads per point, 32 points/block, 2048 blocks. Same _rn Gram-trick
// arithmetic + strict-< insertion + ordered merge tree (lower j preferred on
// ties) matching lax.top_k — passed refcheck 3x.
// ---------------------------------------------------------------------------
__global__ __launch_bounds__(256) void knn_select(
    const float* __restrict__ pos, const float* __restrict__ pos_skip,
    int4* __restrict__ idx4, float4* __restrict__ wgt4,
    const float* __restrict__ W1, const float* __restrict__ W2,
    unsigned short* __restrict__ W1t, unsigned short* __restrict__ W2t)
{
    __shared__ float4 sp[NX_];           // 16 KiB (px,py,pz,|p|^2)
    __shared__ float  md[7][3][32];      // [eighth-1][rank][point]
    __shared__ int    mi[7][3][32];

    const int tid = threadIdx.x;
    const int e   = tid >> 5;            // scan eighth 0..7
    const int p   = tid & 31;            // point slot
    const int y   = blockIdx.x * 32 + p;
    const int b   = y >> 12;             // cloud (4096 fine pts per cloud)

    // folded prep_w (first 384 blocks do one element of each)
    {
        const int id = blockIdx.x * 256 + tid;
        if (id < K1_ * H_) {
            int n = id / K1_, k = id - n * K1_;
            W1t[id] = f2bf(W1[(size_t)k * H_ + n]);
        }
        if (id < K2_ * H_) {
            int n = id >> 8, k = id & 255;
            W2t[id] = f2bf(W2[(size_t)k * H_ + n]);
        }
    }

    for (int j = tid; j < NX_; j += 256) {
        const float* pp = pos + (size_t)(b * NX_ + j) * 3;
        float px = pp[0], py = pp[1], pz = pp[2];
        float pn = __fadd_rn(__fadd_rn(__fmul_rn(px, px), __fmul_rn(py, py)),
                             __fmul_rn(pz, pz));
        sp[j] = make_float4(px, py, pz, pn);
    }
    __syncthreads();

    const float* qp = pos_skip + (size_t)y * 3;
    const float qx = qp[0], qy = qp[1], qz = qp[2];
    const float qn = __fadd_rn(__fadd_rn(__fmul_rn(qx, qx), __fmul_rn(qy, qy)),
                               __fmul_rn(qz, qz));

    float d0 = 3.4e38f, d1 = 3.4e38f, d2 = 3.4e38f;
    int   n0 = 0x7fffffff, n1 = 0x7fffffff, n2 = 0x7fffffff;
    const int j0 = e * 128;
    #pragma unroll 8
    for (int t = 0; t < 128; ++t) {
        const int j = j0 + t;
        const float4 pv = sp[j];
        float dot = __fadd_rn(__fadd_rn(__fmul_rn(qx, pv.x),
                                        __fmul_rn(qy, pv.y)),
                              __fmul_rn(qz, pv.z));
        float dd = __fsub_rn(__fadd_rn(qn, pv.w), __fmul_rn(2.0f, dot));
        if (dd < d2) {
            if (dd < d1) {
                d2 = d1; n2 = n1;
                if (dd < d0) { d1 = d0; n1 = n0; d0 = dd; n0 = j; }
                else         { d1 = dd; n1 = j; }
            } else { d2 = dd; n2 = j; }
        }
    }

    if (e != 0) {
        md[e - 1][0][p] = d0; md[e - 1][1][p] = d1; md[e - 1][2][p] = d2;
        mi[e - 1][0][p] = n0; mi[e - 1][1][p] = n1; mi[e - 1][2][p] = n2;
    }
    __syncthreads();

    if (e == 0) {
        #pragma unroll
        for (int m = 0; m < 7; ++m) {
            const float b0 = md[m][0][p], b1 = md[m][1][p], b2 = md[m][2][p];
            const int  ib0 = mi[m][0][p], ib1 = mi[m][1][p], ib2 = mi[m][2][p];
            const float a0 = d0, a1 = d1, a2 = d2;
            const int  ia0 = n0, ia1 = n1, ia2 = n2;
            if (a0 <= b0) {
                d0 = a0; n0 = ia0;
                if (a1 <= b0) { d1 = a1; n1 = ia1;
                    bool c = (a2 <= b0); d2 = c ? a2 : b0; n2 = c ? ia2 : ib0; }
                else          { d1 = b0; n1 = ib0;
                    bool c = (a1 <= b1); d2 = c ? a1 : b1; n2 = c ? ia1 : ib1; }
            } else {
                d0 = b0; n0 = ib0;
                if (a0 <= b1) { d1 = a0; n1 = ia0;
                    bool c = (a1 <= b1); d2 = c ? a1 : b1; n2 = c ? ia1 : ib1; }
                else          { d1 = b1; n1 = ib1;
                    bool c = (a0 <= b2); d2 = c ? a0 : b2; n2 = c ? ia0 : ib2; }
            }
        }
        const float w0 = 1.0f / (sqrtf(fmaxf(d0, 0.0f)) + 1e-8f);
        const float w1 = 1.0f / (sqrtf(fmaxf(d1, 0.0f)) + 1e-8f);
        const float w2 = 1.0f / (sqrtf(fmaxf(d2, 0.0f)) + 1e-8f);
        const float inv_den = 1.0f / (w0 + w1 + w2 + 1e-8f);
        idx4[y] = make_int4(n0, n1, n2, 0);
        wgt4[y] = make_float4(w0, w1, w2, inv_den);
    }
}

// ---------------------------------------------------------------------------
// Kernel 2: FUSED gather+interp+concat + GEMM1, XCD-chunk-swizzled.
// h1[M][256] = relu(concat(interp, x_skip)[M][384] @ W1 + b1)
// Swizzle: logical block lb = (bid&7)*128 + bid>>3 -> each XCD (bid%8) owns a
// contiguous 128-block chunk = 2 clouds = 2.1 MB of x -> gathers L2-resident.
// Prologue hoists idx4/wgt4 in batches of 8 rows for MLP. LDS 80 KiB
// (As_full 48 + Bs 32), 2 blocks/CU.
// ---------------------------------------------------------------------------
__global__ __launch_bounds__(256, 2) void gemm1_fused(
    const float* __restrict__ x, const float* __restrict__ x_skip,
    const int4* __restrict__ idx4, const float4* __restrict__ wgt4,
    const unsigned short* __restrict__ Bt,   // W1t [256][384] bf16
    const float* __restrict__ bias,          // b1
    unsigned short* __restrict__ outp)       // h1 [M][256] bf16
{
    __shared__ unsigned short As_full[6 * 64 * 64];   // 48 KiB, swizzled slots
    __shared__ unsigned short Bs[256 * 64];           // 32 KiB

    const int tid  = threadIdx.x;
    const int lane = tid & 63;
    const int wave = tid >> 6;
    const int bid  = blockIdx.x;
    const int lb   = (bid & 7) * 128 + (bid >> 3);    // XCD-chunked, bijective
    const int m0   = lb * 64;
    const int r16  = lane & 15, qk = lane >> 4;

    auto stageB = [&](int kt) {
        #pragma unroll
        for (int i = 0; i < 8; ++i) {
            const int row  = (tid >> 3) + i * 32;
            const int slot = (tid & 7) ^ (row & 7);
            gload_lds16(Bt + (size_t)row * K1_ + kt + slot * 8,
                        &Bs[row * 64 + (tid & 7) * 8]);
        }
    };

    stageB(0);

    // ---- fused interp prologue: wave w -> rows [w*16, w*16+16) ----
    {
        const int ks  = lane >> 4;            // K-step of interp cols lane*4
        const int cs  = (lane * 4) & 63;
        const int sl  = cs >> 3;
        const int of  = cs & 7;
        const int ks2  = 4 + (lane >> 5);     // K-step of skip cols 256+lane*2
        const int cs2  = (lane * 2) & 63;
        const int sl2  = cs2 >> 3;
        const int of2  = cs2 & 7;
        #pragma unroll
        for (int batch = 0; batch < 2; ++batch) {
            int4 ids[8]; float4 wts[8];
            #pragma unroll
            for (int i = 0; i < 8; ++i) {
                const int gr = m0 + wave * 16 + batch * 8 + i;
                ids[i] = idx4[gr];
                wts[i] = wgt4[gr];
            }
            #pragma unroll
            for (int i = 0; i < 8; ++i) {
                const int r  = wave * 16 + batch * 8 + i;
                const int gr = m0 + r;
                const float4 wt = wts[i];
                const float* fb = x + (size_t)(gr >> 12) * (NX_ * C_);
                const float4 f0 = *(const float4*)(fb + (size_t)ids[i].x * C_ + lane * 4);
                const float4 f1 = *(const float4*)(fb + (size_t)ids[i].y * C_ + lane * 4);
                const float4 f2 = *(const float4*)(fb + (size_t)ids[i].z * C_ + lane * 4);
                ushort4 o;
                o.x = f2bf((wt.x * f0.x + wt.y * f1.x + wt.z * f2.x) * wt.w);
                o.y = f2bf((wt.x * f0.y + wt.y * f1.y + wt.z * f2.y) * wt.w);
                o.z = f2bf((wt.x * f0.z + wt.y * f1.z + wt.z * f2.z) * wt.w);
                o.w = f2bf((wt.x * f0.w + wt.y * f1.w + wt.z * f2.w) * wt.w);
                *(ushort4*)&As_full[ks * 4096 + r * 64 + (sl ^ (r & 7)) * 8 + of] = o;

                const float2 s2 = *(const float2*)(x_skip + (size_t)gr * CS_ + lane * 2);
                ushort2 os; os.x = f2bf(s2.x); os.y = f2bf(s2.y);
                *(ushort2*)&As_full[ks2 * 4096 + r * 64 + (sl2 ^ (r & 7)) * 8 + of2] = os;
            }
        }
    }
    __syncthreads();        // drains gload vmcnt + prologue ds_writes

    floatx4 acc[4][4] = {};

    #pragma unroll
    for (int t = 0; t < 6; ++t) {
        const unsigned short* At = As_full + t * 4096;
        #pragma unroll
        for (int s = 0; s < 2; ++s) {
            short8 af[4], bf[4];
            #pragma unroll
            for (int m = 0; m < 4; ++m) {
                const int row  = m * 16 + r16;
                const int slot = (s * 4 + qk) ^ (r16 & 7);
                af[m] = *(const short8*)&At[row * 64 + slot * 8];
            }
            #pragma unroll
            for (int n = 0; n < 4; ++n) {
                const int row  = wave * 64 + n * 16 + r16;
                const int slot = (s * 4 + qk) ^ (r16 & 7);
                bf[n] = *(const short8*)&Bs[row * 64 + slot * 8];
            }
            #pragma unroll
            for (int m = 0; m < 4; ++m)
                #pragma unroll
                for (int n = 0; n < 4; ++n)
                    acc[m][n] = __builtin_amdgcn_mfma_f32_16x16x32_bf16(
                        af[m], bf[n], acc[m][n], 0, 0, 0);
        }
        if (t < 5) {
            __syncthreads();             // all waves done reading Bs
            stageB((t + 1) * 64);
            __syncthreads();             // Bs[t+1] ready
        }
    }

    #pragma unroll
    for (int n = 0; n < 4; ++n) {
        const int gc = wave * 64 + n * 16 + r16;
        const float bv = bias[gc];
        #pragma unroll
        for (int m = 0; m < 4; ++m) {
            #pragma unroll
            for (int r = 0; r < 4; ++r) {
                const int gr = m0 + m * 16 + qk * 4 + r;
                float v = fmaxf(acc[m][n][r] + bv, 0.0f);
                outp[(size_t)gr * H_ + gc] = f2bf(v);
            }
        }
    }
}

// ---------------------------------------------------------------------------
// Kernel 3: GEMM2  out[M][256] = relu(h1[M][256] @ W2 + b2), fp32 out.
// Single-buffered As (8 KiB) + Bs (32 KiB) = 40 KiB -> 4 blocks/CU (16
// waves/CU): the per-step stage stall is hidden by co-resident blocks
// (HIP drains vmcnt at barriers, so dbuf prefetch never survived anyway).
// ---------------------------------------------------------------------------
__global__ __launch_bounds__(256, 4) void gemm2_bias_relu(
    const unsigned short* __restrict__ A,   // h1 [M][256] bf16
    const unsigned short* __restrict__ Bt,  // W2t [256][256] bf16
    const float* __restrict__ bias,         // b2
    float* __restrict__ outp)               // [M][256] f32
{
    __shared__ unsigned short As[64 * 64];    // 8 KiB
    __shared__ unsigned short Bs[256 * 64];   // 32 KiB

    const int tid  = threadIdx.x;
    const int lane = tid & 63;
    const int wave = tid >> 6;
    const int m0   = blockIdx.x * 64;
    const int r16  = lane & 15, qk = lane >> 4;

    floatx4 acc[4][4] = {};

    auto stage = [&](int kt) {
        #pragma unroll
        for (int i = 0; i < 2; ++i) {
            const int row  = (tid >> 3) + i * 32;
            const int slot = (tid & 7) ^ (row & 7);
            gload_lds16(A + (size_t)(m0 + row) * K2_ + kt + slot * 8,
                        &As[row * 64 + (tid & 7) * 8]);
        }
        #pragma unroll
        for (int i = 0; i < 8; ++i) {
            const int row  = (tid >> 3) + i * 32;
            const int slot = (tid & 7) ^ (row & 7);
            gload_lds16(Bt + (size_t)row * K2_ + kt + slot * 8,
                        &Bs[row * 64 + (tid & 7) * 8]);
        }
    };

    #pragma unroll
    for (int t = 0; t < 4; ++t) {
        if (t) __syncthreads();          // readers done with previous tile
        stage(t * 64);
        __syncthreads();                 // staged data ready (vmcnt drained)
        #pragma unroll
        for (int s = 0; s < 2; ++s) {
            short8 af[4], bf[4];
            #pragma unroll
            for (int m = 0; m < 4; ++m) {
                const int row  = m * 16 + r16;
                const int slot = (s * 4 + qk) ^ (r16 & 7);
                af[m] = *(const short8*)&As[row * 64 + slot * 8];
            }
            #pragma unroll
            for (int n = 0; n < 4; ++n) {
                const int row  = wave * 64 + n * 16 + r16;
                const int slot = (s * 4 + qk) ^ (r16 & 7);
                bf[n] = *(const short8*)&Bs[row * 64 + slot * 8];
            }
            #pragma unroll
            for (int m = 0; m < 4; ++m)
                #pragma unroll
                for (int n = 0; n < 4; ++n)
                    acc[m][n] = __builtin_amdgcn_mfma_f32_16x16x32_bf16(
                        af[m], bf[n], acc[m][n], 0, 0, 0);
        }
    }

    #pragma unroll
    for (int n = 0; n < 4; ++n) {
        const int gc = wave * 64 + n * 16 + r16;
        const float bv = bias[gc];
        #pragma unroll
        for (int m = 0; m < 4; ++m) {
            #pragma unroll
            for (int r = 0; r < 4; ++r) {
                const int gr = m0 + m * 16 + qk * 4 + r;
                outp[(size_t)gr * H_ + gc] = fmaxf(acc[m][n][r] + bv, 0.0f);
            }
        }
    }
}

// ---------------------------------------------------------------------------
extern "C" void kernel_launch(void* const* d_in, const int* in_sizes, int n_in,
                              void* d_out, int out_size, void* d_ws, size_t ws_size,
                              hipStream_t stream)
{
    const float* x        = (const float*)d_in[0];
    const float* pos      = (const float*)d_in[1];
    const float* x_skip   = (const float*)d_in[3];
    const float* pos_skip = (const float*)d_in[4];
    const float* W1       = (const float*)d_in[6];
    const float* b1       = (const float*)d_in[7];
    const float* W2       = (const float*)d_in[8];
    const float* b2       = (const float*)d_in[9];

    char* ws = (char*)d_ws;
    unsigned short* h1  = (unsigned short*)(ws);                    // 32 MiB
    unsigned short* W1t = (unsigned short*)(ws + 33554432);         // 192 KiB
    unsigned short* W2t = (unsigned short*)(ws + 33751040);         // 128 KiB
    int4*           idx4 = (int4*)(ws + 33882112);                  // 1 MiB
    float4*         wgt4 = (float4*)(ws + 34930688);                // 1 MiB

    hipLaunchKernelGGL(knn_select, dim3(M_ / 32), dim3(256), 0, stream,
                       pos, pos_skip, idx4, wgt4, W1, W2, W1t, W2t);
    hipLaunchKernelGGL(gemm1_fused, dim3(M_ / 64), dim3(256), 0, stream,
                       x, x_skip, idx4, wgt4, W1t, b1, h1);
    hipLaunchKernelGGL(gemm2_bias_relu, dim3(M_ / 64), dim3(256), 0, stream,
                       h1, W2t, b2, (float*)d_out);
}